// Round 5
// baseline (298.066 us; speedup 1.0000x reference)
//
#include <hip/hip_runtime.h>
#include <hip/hip_bf16.h>

// NodeDetector: per-node-masked 2-layer GATv2 forward, delta formulation.
// N=256, C2=64, H=2, E=4352 (incl self loops).
// R5: single fused kernel (256 blocks = 1/CU, device-scope grid barriers,
// graph-safe monotonic ticket counters) + delta-softmax for mutual neighbors
// (phase 2 saves m/denom/numerator/per-edge-logits; phase 3 patches only the
// src==i edges; full recompute only at node i itself).

#define NN 256
#define EDGE_CAP 96   // max in-degree, phase-2 buffers (actual ~35)
#define E2_CAP 64     // max in-degree of node i, phase-3 buffers
#define E_CAP 6144    // max edges (actual 4352)
#define M_CAP 16      // max mutual-neighbor count (actual ~1-6)
#define P_CAP 8       // max parallel edges i->j

// ---- converted-input arena offsets (floats) ----
#define OFF_X      0
#define OFF_E      16384
#define OFF_NP     32768
#define OFF_EP     40960
#define OFF_CW0    49152
#define OFF_CW1    65536
#define OFF_CB     81920
#define OFF_L2W    82048
#define OFF_L2B    90240
#define OFF_MP     90304
#define OFF_NPJ    94400
#define OFF_G1WL   98496
#define OFF_G1BL   106688
#define OFF_G1WR   106816
#define OFF_G1BR   115008
#define OFF_G1ATT  115136
#define OFF_G1BIAS 115264
#define OFF_G2WL   115328
#define OFF_G2BL   123520
#define OFF_G2WR   123648
#define OFF_G2BR   131840
#define OFF_G2ATT  131968
#define OFF_G2BIAS 132096
#define OFF_RECW   132160
#define OFF_RECB   136256
#define W_TOTAL    136320

// ---- persistent device-global scratch ----
__device__ float g_w[W_TOTAL];
__device__ float g_xl0[NN*128], g_xr0[NN*128], g_xlV[NN*128], g_xrV[NN*128];
__device__ float g_xl2_0[NN*128];
__device__ float g_num[NN*128];        // baseline pre-division numerator
__device__ float g_m[NN*2], g_den[NN*2];
__device__ float g_elog[E_CAP*2];      // baseline per-edge logits (by CSR pos)
__device__ int   g_in_ptr[NN+1], g_out_ptr[NN+1];
__device__ int   g_in_src[E_CAP], g_out_dst[E_CAP];
__device__ unsigned g_barcnt[4];       // grid-barrier tickets (monotonic)

// converter block -> (segment, 4096-chunk) static mapping (44 blocks)
__device__ const int c_off[26] = {
  0,16384,32768,40960,49152,65536,81920,82048,90240,90304,94400,98496,
  106688,106816,115008,115136,115264,115328,123520,123648,131840,131968,
  132096,132160,136256,136320};
__device__ const signed char c_seg[44] = {
  0,0,0,0, 1,1,1,1, 2,2, 3,3, 4,4,4,4, 5,5,5,5, 6, 7,7, 8, 9, 10,
  11,11, 12, 13,13, 14, 15, 16, 17,17, 18, 19,19, 20, 21, 22, 23, 24};
__device__ const signed char c_sub[44] = {
  0,1,2,3, 0,1,2,3, 0,1, 0,1, 0,1,2,3, 0,1,2,3, 0, 0,1, 0, 0, 0,
  0,1, 0, 0,1, 0, 0, 0, 0,1, 0, 0,1, 0, 0, 0, 0, 0};

typedef const void* cvp;
__device__ __forceinline__ float b2f(__hip_bfloat16 v) { return __bfloat162float(v); }

__device__ __forceinline__ cvp pick_seg(int s, cvp const* p) { return p[s]; }

// Grid barrier: monotonic ticket counter, never reset (each call adds exactly
// gridDim arrivals; calls are stream-serialized so arrival blocks are
// contiguous). __threadfence = agent-scope release/acquire (L2 wb/inv) for
// cross-XCD visibility of ordinary stores.
__device__ __forceinline__ void gridbar(int k, unsigned nblk) {
  __threadfence();
  __syncthreads();
  if (threadIdx.x == 0) {
    unsigned ticket = atomicAdd(&g_barcnt[k], 1u) + 1u;
    unsigned target = ((ticket + nblk - 1u) / nblk) * nblk;
    while (atomicAdd(&g_barcnt[k], 0u) < target) __builtin_amdgcn_s_sleep(8);
  }
  __syncthreads();
  __threadfence();
}

// ---- phase-overlayed LDS ----
struct P0 { int cin[NN], cou[NN], pin[NN], pou[NN]; };
struct P1 { float sx[64], sE[64], sxp[128], sEp[128], sh0[128], shm[128],
                  sm0[64], sMm[64], sp0[64], sV[64]; };
struct P2 { float sxr[128], satt[128], slog[2][EDGE_CAP], sw[2][EDGE_CAP],
                  sinv[2], sagg[128], sg1[64]; int ssrc[EDGE_CAP]; };
struct P3 {
  float xl2e[E2_CAP*128];
  float g1m[M_CAP*64];
  float sgi[64];
  float sxlVi[128], sxl0i[128], sxri[128];
  float satt[128], satt2[128];
  float slog[2][E2_CAP], sw[2][E2_CAP], sinv[2], sagg[128];
  float xr2i[128], sg[64], dn[128], dd[2];
  int   slotOf[NN];
  unsigned char isInN[NN];
  int ssrc2[E2_CAP], plist[P_CAP], listM[M_CAP];
  int nM, np;
};

__global__ __launch_bounds__(256) void k_fused(
    cvp x, cvp ei_v, cvp out_v,
    cvp i0, cvp i1, cvp i3, cvp i4, cvp i5, cvp i6, cvp i7, cvp i8, cvp i9,
    cvp i10, cvp i11, cvp i12, cvp i13, cvp i14, cvp i15, cvp i16, cvp i17,
    cvp i18, cvp i19, cvp i20, cvp i21, cvp i22, cvp i23, cvp i24, cvp i25,
    int n, int E)
{
  const int t = threadIdx.x, b = blockIdx.x;
  __shared__ union { P0 p0; P1 p1; P2 p2; P3 p3; } S;
  __shared__ int s_cnt;

  // ======== phase 0a: dtype detection (every block, redundant) ========
  if (t == 0) s_cnt = 0;
  __syncthreads();
  {
    const __hip_bfloat16* xb = (const __hip_bfloat16*)x;
    const int lim = n < 4096 ? n : 4096;
    int c = 0;
    for (int i = t; i < lim; i += 256) {
      const float v = b2f(xb[i]);
      if (!(fabsf(v) <= 16.f)) c++;   // counts NaN too
    }
    if (c) atomicAdd(&s_cnt, c);
  }
  __syncthreads();
  const int f = (s_cnt > 64) ? 1 : 0;   // 1 => f32 inputs/output

  // ======== phase 0b: convert inputs / build CSR ========
  if (E > E_CAP) E = E_CAP;
  const int* ei = (const int*)ei_v;
  if (b < 44) {
    cvp segs[25] = {i0,i1,i3,i4,i5,i6,i7,i8,i9,i10,i11,i12,i13,i14,i15,
                    i16,i17,i18,i19,i20,i21,i22,i23,i24,i25};
    const int s = c_seg[b];
    cvp p = pick_seg(s, segs);
    const int off = c_off[s];
    const int base = (int)c_sub[b] * 4096;
    int lim = (c_off[s+1] - off) - base;
    if (lim > 4096) lim = 4096;
    if (f) {
      const float* pf = (const float*)p;
      for (int i = t; i < lim; i += 256) g_w[off+base+i] = pf[base+i];
    } else {
      const __hip_bfloat16* pb = (const __hip_bfloat16*)p;
      for (int i = t; i < lim; i += 256) g_w[off+base+i] = b2f(pb[base+i]);
    }
  } else if (b == 44) {
    S.p0.cin[t] = 0; S.p0.cou[t] = 0;
    __syncthreads();
    for (int e = t; e < E; e += 256) {
      atomicAdd(&S.p0.cin[ei[E+e] & (NN-1)], 1);
      atomicAdd(&S.p0.cou[ei[e]   & (NN-1)], 1);
    }
    __syncthreads();
    // Hillis-Steele inclusive scan (256 elems, 8 steps)
    S.p0.pin[t] = S.p0.cin[t]; S.p0.pou[t] = S.p0.cou[t];
    __syncthreads();
    for (int off = 1; off < NN; off <<= 1) {
      int a = 0, c = 0;
      if (t >= off) { a = S.p0.pin[t-off]; c = S.p0.pou[t-off]; }
      __syncthreads();
      if (t >= off) { S.p0.pin[t] += a; S.p0.pou[t] += c; }
      __syncthreads();
    }
    const int exi = S.p0.pin[t] - S.p0.cin[t];   // exclusive
    const int exo = S.p0.pou[t] - S.p0.cou[t];
    g_in_ptr[t] = exi; g_out_ptr[t] = exo;
    if (t == NN-1) { g_in_ptr[NN] = S.p0.pin[t]; g_out_ptr[NN] = S.p0.pou[t]; }
    S.p0.cin[t] = exi; S.p0.cou[t] = exo;        // reuse as cursors
    __syncthreads();
    for (int e = t; e < E; e += 256) {
      const int s = ei[e] & (NN-1), d = ei[E+e] & (NN-1);
      g_in_src[atomicAdd(&S.p0.cin[d], 1)] = s;
      g_out_dst[atomicAdd(&S.p0.cou[s], 1)] = d;
    }
  }
  gridbar(0, gridDim.x);

  // ======== phase 1: dense precompute for node j=b ========
  {
    const int j = b;
    if (t < 64) { S.p1.sx[t] = g_w[OFF_X + j*64+t]; S.p1.sE[t] = g_w[OFF_E + j*64+t]; }
    __syncthreads();
    if (t < 128) {
      float a = 0.f, c = 0.f;
      #pragma unroll
      for (int k = 0; k < 64; ++k) {
        a += S.p1.sx[k] * g_w[OFF_NP + k*128+t];
        c += S.p1.sE[k] * g_w[OFF_EP + k*128+t];
      }
      S.p1.sxp[t] = a; S.p1.sEp[t] = c;
    }
    __syncthreads();
    if (t < 128) {
      float xw1 = 0.f, ew0 = 0.f;
      #pragma unroll
      for (int k = 0; k < 128; ++k) {
        xw1 += S.p1.sxp[k] * g_w[OFF_CW1 + k*128+t];
        ew0 += S.p1.sEp[k] * g_w[OFF_CW0 + k*128+t];
      }
      const float cb = g_w[OFF_CB + t];
      S.p1.sh0[t] = tanhf(ew0 + xw1 + cb);
      S.p1.shm[t] = tanhf(ew0 + cb);
    }
    __syncthreads();
    if (t < 64) {
      float m0 = g_w[OFF_L2B + t], Mm = m0;
      #pragma unroll
      for (int k = 0; k < 128; ++k) {
        const float w = g_w[OFF_L2W + k*64+t];
        m0 += S.p1.sh0[k]*w; Mm += S.p1.shm[k]*w;
      }
      S.p1.sm0[t] = m0; S.p1.sMm[t] = Mm;
    }
    __syncthreads();
    if (t < 64) {
      float p = 0.f, v = 0.f;
      #pragma unroll
      for (int k = 0; k < 64; ++k) {
        p += S.p1.sm0[k] * g_w[OFF_NPJ + k*64+t];
        v += S.p1.sMm[k] * g_w[OFF_MP + k*64+t];
      }
      S.p1.sp0[t] = p; S.p1.sV[t] = v;
    }
    __syncthreads();
    if (t < 128) {
      float l0 = g_w[OFF_G1BL + t], r0 = g_w[OFF_G1BR + t];
      float lV = l0, rV = r0;
      #pragma unroll
      for (int k = 0; k < 64; ++k) {
        const float wl = g_w[OFF_G1WL + k*128+t], wr = g_w[OFF_G1WR + k*128+t];
        l0 += S.p1.sp0[k]*wl; r0 += S.p1.sp0[k]*wr;
        lV += S.p1.sV[k]*wl;  rV += S.p1.sV[k]*wr;
      }
      g_xl0[j*128+t] = l0; g_xr0[j*128+t] = r0;
      g_xlV[j*128+t] = lV; g_xrV[j*128+t] = rV;
    }
  }
  gridbar(1, gridDim.x);

  // ======== phase 2: baseline layer-1 attention + stats for node j=b ========
  {
    const int j = b;
    const int base = g_in_ptr[j];
    int nE = g_in_ptr[j+1] - base;
    if (nE > EDGE_CAP) nE = EDGE_CAP;
    if (t < 128) { S.p2.sxr[t] = g_xr0[j*128+t]; S.p2.satt[t] = g_w[OFF_G1ATT + t]; }
    for (int e = t; e < nE; e += 256) S.p2.ssrc[e] = g_in_src[base+e];
    __syncthreads();
    for (int idx = t; idx < nE*2; idx += 256) {
      const int e = idx >> 1, h = idx & 1, s = S.p2.ssrc[e];
      const float* xls = g_xl0 + s*128 + h*64;
      float acc = 0.f;
      #pragma unroll
      for (int c = 0; c < 64; ++c) {
        float v = xls[c] + S.p2.sxr[h*64+c];
        v = v > 0.f ? v : 0.2f*v;
        acc += S.p2.satt[h*64+c]*v;
      }
      S.p2.slog[h][e] = acc;
      g_elog[(base+e)*2+h] = acc;
    }
    __syncthreads();
    if (t < 128) {
      const int h = t >> 6, lane = t & 63;
      float m = -1e30f;
      for (int e = lane; e < nE; e += 64) m = fmaxf(m, S.p2.slog[h][e]);
      for (int o = 1; o < 64; o <<= 1) m = fmaxf(m, __shfl_xor(m, o));
      float ssum = 0.f;
      for (int e = lane; e < nE; e += 64) {
        const float w = __expf(S.p2.slog[h][e]-m); S.p2.sw[h][e] = w; ssum += w;
      }
      for (int o = 1; o < 64; o <<= 1) ssum += __shfl_xor(ssum, o);
      if (lane == 0) {
        S.p2.sinv[h] = 1.f/(ssum + 1e-16f);
        g_m[j*2+h] = m; g_den[j*2+h] = ssum;
      }
    }
    __syncthreads();
    if (t < 128) {
      const int h = t >> 6, c = t & 63;
      float acc = 0.f;
      for (int e = 0; e < nE; ++e) acc += S.p2.sw[h][e]*g_xl0[S.p2.ssrc[e]*128 + h*64 + c];
      g_num[j*128+t] = acc;                 // pre-division numerator
      S.p2.sagg[t] = acc*S.p2.sinv[h];
    }
    __syncthreads();
    if (t < 64) {
      float g = 0.5f*(S.p2.sagg[t]+S.p2.sagg[64+t]) + g_w[OFF_G1BIAS + t];
      g = g > 0.f ? g : expm1f(g);
      S.p2.sg1[t] = g;
    }
    __syncthreads();
    if (t < 128) {
      float acc = g_w[OFF_G2BL + t];
      #pragma unroll
      for (int k = 0; k < 64; ++k) acc += S.p2.sg1[k]*g_w[OFF_G2WL + k*128+t];
      g_xl2_0[j*128+t] = acc;
    }
  }
  gridbar(2, gridDim.x);

  // ======== phase 3: per-mask-iteration, i=b ========
  {
    const int i = b;
    if (t < NN) { S.p3.slotOf[t] = -1; S.p3.isInN[t] = 0; }
    if (t == 0) { S.p3.nM = 0; }
    if (t < 128) {
      S.p3.satt[t]  = g_w[OFF_G1ATT + t];
      S.p3.satt2[t] = g_w[OFF_G2ATT + t];
      S.p3.sxlVi[t] = g_xlV[i*128+t];
      S.p3.sxl0i[t] = g_xl0[i*128+t];
      S.p3.sxri[t]  = g_xrV[i*128+t];
    }
    __syncthreads();
    if (t == 0) S.p3.slotOf[i] = 0;

    // in-edges of i + in-neighbor bitmap
    const int b2 = g_in_ptr[i];
    int nE2 = g_in_ptr[i+1] - b2;
    if (nE2 > E2_CAP) nE2 = E2_CAP;
    for (int e = t; e < nE2; e += 256) {
      const int s = g_in_src[b2+e];
      S.p3.ssrc2[e] = s;
      S.p3.isInN[s] = 1;
    }
    __syncthreads();

    // mutual-neighbor list (slots 1..nM)
    const int ob = g_out_ptr[i], onE = g_out_ptr[i+1] - ob;
    for (int e = t; e < onE; e += 256) {
      const int d = g_out_dst[ob+e];
      if (d != i && S.p3.isInN[d]) {
        if (atomicCAS(&S.p3.slotOf[d], -1, -2) == -1) {
          const int p = atomicAdd(&S.p3.nM, 1);
          if (p < M_CAP) { S.p3.listM[p] = d; S.p3.slotOf[d] = p + 1; }
          else S.p3.slotOf[d] = -1;
        }
      }
    }
    __syncthreads();
    int nMl = S.p3.nM; if (nMl > M_CAP) nMl = M_CAP;

    // ---- full recompute of layer-1 at node i (xr -> xrV, src i -> xlV) ----
    for (int idx = t; idx < nE2*2; idx += 256) {
      const int e = idx >> 1, h = idx & 1, s = S.p3.ssrc2[e];
      const float* xls = (s == i) ? (S.p3.sxlVi + h*64) : (g_xl0 + s*128 + h*64);
      float acc = 0.f;
      #pragma unroll
      for (int c = 0; c < 64; ++c) {
        float v = xls[c] + S.p3.sxri[h*64+c];
        v = v > 0.f ? v : 0.2f*v;
        acc += S.p3.satt[h*64+c]*v;
      }
      S.p3.slog[h][e] = acc;
    }
    __syncthreads();
    if (t < 128) {
      const int h = t >> 6, lane = t & 63;
      float m = -1e30f;
      for (int e = lane; e < nE2; e += 64) m = fmaxf(m, S.p3.slog[h][e]);
      for (int o = 1; o < 64; o <<= 1) m = fmaxf(m, __shfl_xor(m, o));
      float ssum = 0.f;
      for (int e = lane; e < nE2; e += 64) {
        const float w = __expf(S.p3.slog[h][e]-m); S.p3.sw[h][e] = w; ssum += w;
      }
      for (int o = 1; o < 64; o <<= 1) ssum += __shfl_xor(ssum, o);
      if (lane == 0) S.p3.sinv[h] = 1.f/(ssum + 1e-16f);
    }
    __syncthreads();
    if (t < 128) {
      const int h = t >> 6, c = t & 63;
      float acc = 0.f;
      for (int e = 0; e < nE2; ++e) {
        const int s = S.p3.ssrc2[e];
        const float* xls = (s == i) ? S.p3.sxlVi : (g_xl0 + s*128);
        acc += S.p3.sw[h][e]*xls[h*64+c];
      }
      S.p3.sagg[t] = acc*S.p3.sinv[h];
    }
    __syncthreads();
    if (t < 64) {
      float g = 0.5f*(S.p3.sagg[t]+S.p3.sagg[64+t]) + g_w[OFF_G1BIAS + t];
      g = g > 0.f ? g : expm1f(g);
      S.p3.sgi[t] = g;
    }
    __syncthreads();

    // ---- delta-softmax update for each mutual neighbor j ----
    for (int m = 0; m < nMl; ++m) {
      const int j = S.p3.listM[m];
      const int jb = g_in_ptr[j], jd = g_in_ptr[j+1] - jb;
      if (t == 0) S.p3.np = 0;
      if (t < 128) S.p3.dn[t] = 0.f;
      if (t < 2) S.p3.dd[t] = 0.f;
      __syncthreads();
      for (int p = t; p < jd; p += 256)
        if (g_in_src[jb+p] == i) {
          const int q = atomicAdd(&S.p3.np, 1);
          if (q < P_CAP) S.p3.plist[q] = jb + p;
        }
      __syncthreads();
      int npl = S.p3.np; if (npl > P_CAP) npl = P_CAP;
      if (t < 128) {
        const int h = t >> 6;
        const float mj = g_m[j*2+h];
        // new logit for edge i->j (same for all parallel edges)
        float u = S.p3.sxlVi[t] + g_xr0[j*128+t];
        u = u > 0.f ? u : 0.2f*u;
        float ln = S.p3.satt[t]*u;
        for (int o = 1; o < 64; o <<= 1) ln += __shfl_xor(ln, o);
        const float wn1 = __expf(ln - mj);
        float dnum = 0.f, dden = 0.f;
        for (int q = 0; q < npl; ++q) {
          const float lo = g_elog[S.p3.plist[q]*2+h];
          const float wo = __expf(lo - mj);
          dnum += wn1*S.p3.sxlVi[t] - wo*S.p3.sxl0i[t];
          dden += wn1 - wo;
        }
        S.p3.dn[t] = dnum;
        if ((t & 63) == 0) S.p3.dd[h] = dden;
      }
      __syncthreads();
      if (t < 64) {
        const float d0 = g_den[j*2+0] + S.p3.dd[0] + 1e-16f;
        const float d1 = g_den[j*2+1] + S.p3.dd[1] + 1e-16f;
        const float n0 = g_num[j*128+t]    + S.p3.dn[t];
        const float n1 = g_num[j*128+64+t] + S.p3.dn[64+t];
        float g = 0.5f*(n0/d0 + n1/d1) + g_w[OFF_G1BIAS + t];
        g = g > 0.f ? g : expm1f(g);
        S.p3.g1m[m*64+t] = g;
      }
      __syncthreads();
    }

    // ---- layer 2 at node i ----
    for (int idx = t; idx < nE2*128; idx += 256) {
      const int e = idx >> 7, c = idx & 127, s = S.p3.ssrc2[e];
      const int sl = S.p3.slotOf[s];
      float v;
      if (sl >= 0) {
        const float* g1r = (sl == 0) ? S.p3.sgi : (S.p3.g1m + (sl-1)*64);
        v = g_w[OFF_G2BL + c];
        #pragma unroll
        for (int k = 0; k < 64; ++k) v += g1r[k]*g_w[OFF_G2WL + k*128+c];
      } else {
        v = g_xl2_0[s*128+c];
      }
      S.p3.xl2e[e*128+c] = v;
    }
    if (t < 128) {
      float v = g_w[OFF_G2BR + t];
      #pragma unroll
      for (int k = 0; k < 64; ++k) v += S.p3.sgi[k]*g_w[OFF_G2WR + k*128+t];
      S.p3.xr2i[t] = v;
    }
    __syncthreads();
    for (int idx = t; idx < nE2*2; idx += 256) {
      const int e = idx >> 1, h = idx & 1;
      const float* xle = S.p3.xl2e + e*128 + h*64;
      float acc = 0.f;
      #pragma unroll
      for (int c = 0; c < 64; ++c) {
        float v = xle[c] + S.p3.xr2i[h*64+c];
        v = v > 0.f ? v : 0.2f*v;
        acc += S.p3.satt2[h*64+c]*v;
      }
      S.p3.slog[h][e] = acc;
    }
    __syncthreads();
    if (t < 128) {
      const int h = t >> 6, lane = t & 63;
      float m = -1e30f;
      for (int e = lane; e < nE2; e += 64) m = fmaxf(m, S.p3.slog[h][e]);
      for (int o = 1; o < 64; o <<= 1) m = fmaxf(m, __shfl_xor(m, o));
      float ssum = 0.f;
      for (int e = lane; e < nE2; e += 64) {
        const float w = __expf(S.p3.slog[h][e]-m); S.p3.sw[h][e] = w; ssum += w;
      }
      for (int o = 1; o < 64; o <<= 1) ssum += __shfl_xor(ssum, o);
      if (lane == 0) S.p3.sinv[h] = 1.f/(ssum + 1e-16f);
    }
    __syncthreads();
    if (t < 128) {
      const int h = t >> 6, c = t & 63;
      float acc = 0.f;
      for (int e = 0; e < nE2; ++e) acc += S.p3.sw[h][e]*S.p3.xl2e[e*128 + h*64 + c];
      S.p3.sagg[t] = acc*S.p3.sinv[h];
    }
    __syncthreads();
    if (t < 64) {
      float g = 0.5f*(S.p3.sagg[t]+S.p3.sagg[64+t]) + g_w[OFF_G2BIAS + t];
      g = g > 0.f ? g : expm1f(g);
      S.p3.sg[t] = g;
    }
    __syncthreads();
    if (t < 64) {
      float v = g_w[OFF_RECB + t];
      #pragma unroll
      for (int c = 0; c < 64; ++c) v += S.p3.sg[c]*g_w[OFF_RECW + c*64+t];
      const float r = tanhf(v);
      if (f) ((float*)out_v)[i*64+t] = r;
      else   ((__hip_bfloat16*)out_v)[i*64+t] = __float2bfloat16(r);
    }
  }
}

// ---------------------------------------------------------------------------
extern "C" void kernel_launch(void* const* d_in, const int* in_sizes, int n_in,
                              void* d_out, int out_size, void* d_ws, size_t ws_size,
                              hipStream_t stream)
{
  const int E = in_sizes[2] / 2;
  k_fused<<<NN, 256, 0, stream>>>(
      d_in[0], d_in[2], d_out,
      d_in[0], d_in[1], d_in[3], d_in[4], d_in[5], d_in[6], d_in[7],
      d_in[8], d_in[9], d_in[10], d_in[11], d_in[12], d_in[13], d_in[14],
      d_in[15], d_in[16], d_in[17], d_in[18], d_in[19], d_in[20], d_in[21],
      d_in[22], d_in[23], d_in[24], d_in[25],
      in_sizes[0], E);
}

// Round 6
// 170.474 us; speedup vs baseline: 1.7485x; 1.7485x over previous
//
#include <hip/hip_runtime.h>
#include <hip/hip_bf16.h>

// NodeDetector: per-node-masked 2-layer GATv2 forward, delta formulation.
// N=256, C2=64, H=2, E=4352 (incl self loops).
// R6: back to 4 launches (R5 showed software grid barriers force L2
// writeback/invalidate per phase on gfx950 => 2x regression; kernel boundary
// is the cheap device barrier). Ports R5's delta-softmax into k_periter with
// thread-partitioned concurrency (t<128: node-i softmax pipeline, t>=128:
// mutual-neighbor delta updates) and fused agg+elu stages. Parallel scan in
// k_init.

#define NN 256
#define EDGE_CAP 96   // max in-degree, k_l1base buffers (actual ~35)
#define E2_CAP 64     // max in-degree of node i, k_periter buffers
#define E_CAP 6144    // max edges (actual 4352)
#define M_CAP 8       // max mutual-neighbor count tracked (actual ~1-5)

// ---- converted-input arena offsets (floats) ----
#define OFF_X      0
#define OFF_E      16384
#define OFF_NP     32768
#define OFF_EP     40960
#define OFF_CW0    49152
#define OFF_CW1    65536
#define OFF_CB     81920
#define OFF_L2W    82048
#define OFF_L2B    90240
#define OFF_MP     90304
#define OFF_NPJ    94400
#define OFF_G1WL   98496
#define OFF_G1BL   106688
#define OFF_G1WR   106816
#define OFF_G1BR   115008
#define OFF_G1ATT  115136
#define OFF_G1BIAS 115264
#define OFF_G2WL   115328
#define OFF_G2BL   123520
#define OFF_G2WR   123648
#define OFF_G2BR   131840
#define OFF_G2ATT  131968
#define OFF_G2BIAS 132096
#define OFF_RECW   132160
#define OFF_RECB   136256
#define W_TOTAL    136320

// ---- persistent device-global scratch (fully rewritten every call) ----
__device__ float g_w[W_TOTAL];
__device__ float g_xl0[NN*128], g_xr0[NN*128], g_xlV[NN*128], g_xrV[NN*128];
__device__ float g_xl2_0[NN*128];
__device__ float g_num[NN*128];        // baseline pre-division numerator
__device__ float g_m[NN*2], g_den[NN*2];
__device__ float g_elog[E_CAP*2];      // baseline per-edge logits (CSR pos)
__device__ int   g_in_ptr[NN+1], g_out_ptr[NN+1];
__device__ int   g_in_src[E_CAP], g_out_dst[E_CAP];
__device__ int   g_f32;

// converter block -> (segment, 4096-chunk) static mapping (44 blocks)
__device__ const int c_off[26] = {
  0,16384,32768,40960,49152,65536,81920,82048,90240,90304,94400,98496,
  106688,106816,115008,115136,115264,115328,123520,123648,131840,131968,
  132096,132160,136256,136320};
__device__ const signed char c_seg[44] = {
  0,0,0,0, 1,1,1,1, 2,2, 3,3, 4,4,4,4, 5,5,5,5, 6, 7,7, 8, 9, 10,
  11,11, 12, 13,13, 14, 15, 16, 17,17, 18, 19,19, 20, 21, 22, 23, 24};
__device__ const signed char c_sub[44] = {
  0,1,2,3, 0,1,2,3, 0,1, 0,1, 0,1,2,3, 0,1,2,3, 0, 0,1, 0, 0, 0,
  0,1, 0, 0,1, 0, 0, 0, 0,1, 0, 0,1, 0, 0, 0, 0, 0};

typedef const void* cvp;
__device__ __forceinline__ float b2f(__hip_bfloat16 v) { return __bfloat162float(v); }

// ---------------------------------------------------------------------------
// K0: 45 blocks. All blocks: dtype detect (f32 misread as bf16 => ~half of
// values decode |v|>16 or NaN; bf16 N(0,1) has none). Blocks 0..43 convert a
// 4096-chunk of one input into the f32 arena; block 44 builds CSR with a
// parallel Hillis-Steele scan.
// ---------------------------------------------------------------------------
__global__ __launch_bounds__(256) void k_init(
    cvp x, cvp E_emb, cvp node_proj, cvp emb_proj,
    cvp conv_w0, cvp conv_w1, cvp conv_b, cvp lin2_w, cvp lin2_b,
    cvp masked_proj, cvp normal_proj,
    cvp g1_wl, cvp g1_bl, cvp g1_wr, cvp g1_br, cvp g1_att, cvp g1_bias,
    cvp g2_wl, cvp g2_bl, cvp g2_wr, cvp g2_br, cvp g2_att, cvp g2_bias,
    cvp rec_w, cvp rec_b,
    int n, const int* __restrict__ ei, int E)
{
  const int t = threadIdx.x, b = blockIdx.x;
  __shared__ int s_cnt;
  if (t == 0) s_cnt = 0;
  __syncthreads();
  {
    const __hip_bfloat16* xb = (const __hip_bfloat16*)x;
    const int lim = n < 4096 ? n : 4096;
    int c = 0;
    for (int i = t; i < lim; i += 256) {
      const float v = b2f(xb[i]);
      if (!(fabsf(v) <= 16.f)) c++;
    }
    if (c) atomicAdd(&s_cnt, c);
  }
  __syncthreads();
  const int f = (s_cnt > 64) ? 1 : 0;

  if (b < 44) {
    cvp segs[25] = {x, E_emb, node_proj, emb_proj, conv_w0, conv_w1, conv_b,
                    lin2_w, lin2_b, masked_proj, normal_proj,
                    g1_wl, g1_bl, g1_wr, g1_br, g1_att, g1_bias,
                    g2_wl, g2_bl, g2_wr, g2_br, g2_att, g2_bias,
                    rec_w, rec_b};
    const int s = c_seg[b];
    cvp p = segs[s];
    const int off = c_off[s];
    const int base = (int)c_sub[b] * 4096;
    int lim = (c_off[s+1] - off) - base;
    if (lim > 4096) lim = 4096;
    if (f) {
      const float* pf = (const float*)p;
      for (int i = t; i < lim; i += 256) g_w[off+base+i] = pf[base+i];
    } else {
      const __hip_bfloat16* pb = (const __hip_bfloat16*)p;
      for (int i = t; i < lim; i += 256) g_w[off+base+i] = b2f(pb[base+i]);
    }
    return;
  }

  // ---- block 44: publish dtype + CSR build (parallel scan) ----
  __shared__ int cin[NN], cou[NN], pin[NN], pou[NN];
  if (E > E_CAP) E = E_CAP;
  if (t == 0) g_f32 = f;
  cin[t] = 0; cou[t] = 0;
  __syncthreads();
  for (int e = t; e < E; e += 256) {
    atomicAdd(&cin[ei[E+e] & (NN-1)], 1);
    atomicAdd(&cou[ei[e]   & (NN-1)], 1);
  }
  __syncthreads();
  pin[t] = cin[t]; pou[t] = cou[t];
  __syncthreads();
  for (int off = 1; off < NN; off <<= 1) {
    int a = 0, c = 0;
    if (t >= off) { a = pin[t-off]; c = pou[t-off]; }
    __syncthreads();
    if (t >= off) { pin[t] += a; pou[t] += c; }
    __syncthreads();
  }
  const int exi = pin[t] - cin[t];   // exclusive prefix
  const int exo = pou[t] - cou[t];
  g_in_ptr[t] = exi; g_out_ptr[t] = exo;
  if (t == NN-1) { g_in_ptr[NN] = pin[t]; g_out_ptr[NN] = pou[t]; }
  cin[t] = exi; cou[t] = exo;        // reuse as cursors
  __syncthreads();
  for (int e = t; e < E; e += 256) {
    const int s = ei[e] & (NN-1), d = ei[E+e] & (NN-1);
    g_in_src[atomicAdd(&cin[d], 1)] = s;
    g_out_dst[atomicAdd(&cou[s], 1)] = d;
  }
}

// ---------------------------------------------------------------------------
// K1: shared dense precompute. One block per node j (128 threads), pure f32.
// ---------------------------------------------------------------------------
__global__ __launch_bounds__(128) void k_dense()
{
  const int j = blockIdx.x, t = threadIdx.x;
  __shared__ float sx[64], sE[64], sxp[128], sEp[128], sh0[128], shm[128],
                   sm0[64], sMm[64], sp0[64], sV[64];
  if (t < 64) { sx[t] = g_w[OFF_X + j*64+t]; sE[t] = g_w[OFF_E + j*64+t]; }
  __syncthreads();
  float a = 0.f, b = 0.f;
  #pragma unroll
  for (int k = 0; k < 64; ++k) {
    a += sx[k] * g_w[OFF_NP + k*128+t];
    b += sE[k] * g_w[OFF_EP + k*128+t];
  }
  sxp[t] = a; sEp[t] = b;
  __syncthreads();
  float xw1 = 0.f, ew0 = 0.f;
  #pragma unroll
  for (int k = 0; k < 128; ++k) {
    xw1 += sxp[k] * g_w[OFF_CW1 + k*128+t];
    ew0 += sEp[k] * g_w[OFF_CW0 + k*128+t];
  }
  const float cb = g_w[OFF_CB + t];
  sh0[t] = tanhf(ew0 + xw1 + cb);
  shm[t] = tanhf(ew0 + cb);
  __syncthreads();
  if (t < 64) {
    float m0 = g_w[OFF_L2B + t], Mm = m0;
    #pragma unroll
    for (int k = 0; k < 128; ++k) {
      const float w = g_w[OFF_L2W + k*64+t];
      m0 += sh0[k]*w; Mm += shm[k]*w;
    }
    sm0[t] = m0; sMm[t] = Mm;
  }
  __syncthreads();
  if (t < 64) {
    float p = 0.f, v = 0.f;
    #pragma unroll
    for (int k = 0; k < 64; ++k) {
      p += sm0[k] * g_w[OFF_NPJ + k*64+t];
      v += sMm[k] * g_w[OFF_MP + k*64+t];
    }
    sp0[t] = p; sV[t] = v;
  }
  __syncthreads();
  float l0 = g_w[OFF_G1BL + t], r0 = g_w[OFF_G1BR + t];
  float lV = l0, rV = r0;
  #pragma unroll
  for (int k = 0; k < 64; ++k) {
    const float wl = g_w[OFF_G1WL + k*128+t], wr = g_w[OFF_G1WR + k*128+t];
    l0 += sp0[k]*wl; r0 += sp0[k]*wr;
    lV += sV[k]*wl;  rV += sV[k]*wr;
  }
  g_xl0[j*128+t] = l0; g_xr0[j*128+t] = r0;
  g_xlV[j*128+t] = lV; g_xrV[j*128+t] = rV;
}

// ---------------------------------------------------------------------------
// K2: baseline layer-1 attention for node j + softmax state for delta path:
// g_m/g_den (per head), g_num (pre-division numerator), g_elog (per-edge
// logits). Also xl2_0 = elu(head-mean) @ g2_wl + g2_bl.
// ---------------------------------------------------------------------------
__global__ __launch_bounds__(128) void k_l1base()
{
  const int j = blockIdx.x, t = threadIdx.x;
  __shared__ float sxr[128], satt[128], slog[2][EDGE_CAP], sw[2][EDGE_CAP];
  __shared__ float sinv[2], sg1[64];
  __shared__ int ssrc[EDGE_CAP];
  const int base = g_in_ptr[j];
  int nE = g_in_ptr[j+1] - base;
  if (nE > EDGE_CAP) nE = EDGE_CAP;
  sxr[t] = g_xr0[j*128+t];
  satt[t] = g_w[OFF_G1ATT + t];
  for (int e = t; e < nE; e += 128) ssrc[e] = g_in_src[base+e];
  __syncthreads();
  for (int idx = t; idx < nE*2; idx += 128) {
    const int e = idx >> 1, h = idx & 1, s = ssrc[e];
    const float* xls = g_xl0 + s*128 + h*64;
    float acc = 0.f;
    #pragma unroll
    for (int c = 0; c < 64; ++c) {
      float v = xls[c] + sxr[h*64+c];
      v = v > 0.f ? v : 0.2f*v;
      acc += satt[h*64+c]*v;
    }
    slog[h][e] = acc;
    g_elog[(base+e)*2+h] = acc;
  }
  __syncthreads();
  {
    const int h = t >> 6, lane = t & 63;
    float m = -1e30f;
    for (int e = lane; e < nE; e += 64) m = fmaxf(m, slog[h][e]);
    for (int o = 1; o < 64; o <<= 1) m = fmaxf(m, __shfl_xor(m, o));
    float ssum = 0.f;
    for (int e = lane; e < nE; e += 64) {
      const float w = __expf(slog[h][e]-m); sw[h][e] = w; ssum += w;
    }
    for (int o = 1; o < 64; o <<= 1) ssum += __shfl_xor(ssum, o);
    if (lane == 0) {
      sinv[h] = 1.f/(ssum + 1e-16f);
      g_m[j*2+h] = m; g_den[j*2+h] = ssum;
    }
  }
  __syncthreads();
  if (t < 64) {   // fused agg (both heads) + numerator save + elu
    float a0 = 0.f, a1 = 0.f;
    for (int e = 0; e < nE; ++e) {
      const float* xs = g_xl0 + ssrc[e]*128;
      a0 += sw[0][e]*xs[t];
      a1 += sw[1][e]*xs[64+t];
    }
    g_num[j*128+t] = a0; g_num[j*128+64+t] = a1;
    float g = 0.5f*(a0*sinv[0] + a1*sinv[1]) + g_w[OFF_G1BIAS + t];
    g = g > 0.f ? g : expm1f(g);
    sg1[t] = g;
  }
  __syncthreads();
  float acc = g_w[OFF_G2BL + t];
  #pragma unroll
  for (int k = 0; k < 64; ++k) acc += sg1[k]*g_w[OFF_G2WL + k*128+t];
  g_xl2_0[j*128+t] = acc;
}

// ---------------------------------------------------------------------------
// K3 shared state + delta helper
// ---------------------------------------------------------------------------
struct P3s {
  float xl2e[E2_CAP*128];
  float rtmp[M_CAP*128];      // per-mutual per-head ratio terms
  float g1m[M_CAP*64];        // finalized updated g1 for mutual neighbors
  float sgi[64];              // updated g1 at node i
  float sxlVi[128], sxl0i[128], sxri[128];
  float satt[128], satt2[128];
  float slog[2][E2_CAP], sw[2][E2_CAP], sinv[2];
  float xr2i[128], sg[64];
  int   slotOf[NN];
  unsigned char isInN[NN];
  int   ssrc2[E2_CAP], listM[M_CAP];
  int   nM;
};

// delta-softmax update for mutual neighbor slot m; called by threads 128..255
// (wave-aligned: t 128..191 = head 0, t 192..255 = head 1).
__device__ __forceinline__ void delta_one(P3s& S, int m, int nMl, int i, int t)
{
  if (m >= nMl) return;
  const int lt = t - 128, h = lt >> 6, c = lt & 63;
  const int j = S.listM[m];
  const float mj = g_m[j*2+h];
  // new logit for edge i->j (identical for parallel copies)
  float u = S.sxlVi[lt] + g_xr0[j*128+lt];
  u = u > 0.f ? u : 0.2f*u;
  float ln = S.satt[lt]*u;
  for (int o = 1; o < 64; o <<= 1) ln += __shfl_xor(ln, o);
  const float wn1 = __expf(ln - mj);
  // old contributions of all parallel i->j edges
  const int jb = g_in_ptr[j], jd = g_in_ptr[j+1] - jb;
  float wo = 0.f; int cnt = 0;
  for (int p = c; p < jd; p += 64)
    if (g_in_src[jb+p] == i) { wo += __expf(g_elog[(jb+p)*2+h] - mj); cnt++; }
  for (int o = 1; o < 64; o <<= 1) {
    wo += __shfl_xor(wo, o); cnt += __shfl_xor(cnt, o);
  }
  const float dd = (float)cnt*wn1 - wo;
  const float dn = (float)cnt*wn1*S.sxlVi[lt] - wo*S.sxl0i[lt];
  S.rtmp[m*128+lt] = (g_num[j*128+lt] + dn) / (g_den[j*2+h] + dd + 1e-16f);
}

// ---------------------------------------------------------------------------
// K3: per-mask-iteration. Block i: full L1 recompute at node i (t<128 pipe),
// delta-softmax for mutual neighbors (t>=128, concurrent), then layer-2
// attention at node i, reconstruction head, tanh, output.
// ---------------------------------------------------------------------------
__global__ __launch_bounds__(256) void k_periter(void* out)
{
  const int i = blockIdx.x, t = threadIdx.x;
  __shared__ P3s S;

  // ---- stage A: init + broadcast loads ----
  if (t < NN) { S.slotOf[t] = -1; S.isInN[t] = 0; }
  if (t == 0) S.nM = 0;
  if (t < 128) {
    S.satt[t]  = g_w[OFF_G1ATT + t];
    S.satt2[t] = g_w[OFF_G2ATT + t];
    S.sxlVi[t] = g_xlV[i*128+t];
    S.sxl0i[t] = g_xl0[i*128+t];
    S.sxri[t]  = g_xrV[i*128+t];
  }
  __syncthreads();
  if (t == 0) S.slotOf[i] = 0;

  // ---- stage B: in-edges of i + in-neighbor bitmap ----
  const int b2 = g_in_ptr[i];
  int nE2 = g_in_ptr[i+1] - b2;
  if (nE2 > E2_CAP) nE2 = E2_CAP;
  for (int e = t; e < nE2; e += 256) {
    const int s = g_in_src[b2+e];
    S.ssrc2[e] = s;
    S.isInN[s] = 1;
  }
  __syncthreads();

  // ---- stage C: mutual-neighbor set + L1 logits at node i ----
  const int ob = g_out_ptr[i], onE = g_out_ptr[i+1] - ob;
  for (int e = t; e < onE; e += 256) {
    const int d = g_out_dst[ob+e];
    if (d != i && S.isInN[d]) {
      if (atomicCAS(&S.slotOf[d], -1, -2) == -1) {
        const int p = atomicAdd(&S.nM, 1);
        if (p < M_CAP) { S.listM[p] = d; S.slotOf[d] = p + 1; }
        else S.slotOf[d] = -1;
      }
    }
  }
  for (int idx = t; idx < nE2*2; idx += 256) {
    const int e = idx >> 1, h = idx & 1, s = S.ssrc2[e];
    const float* xls = (s == i) ? (S.sxlVi + h*64) : (g_xl0 + s*128 + h*64);
    float acc = 0.f;
    #pragma unroll
    for (int c = 0; c < 64; ++c) {
      float v = xls[c] + S.sxri[h*64+c];
      v = v > 0.f ? v : 0.2f*v;
      acc += S.satt[h*64+c]*v;
    }
    S.slog[h][e] = acc;
  }
  __syncthreads();
  const int nMl = S.nM > M_CAP ? M_CAP : S.nM;

  // ---- stage D: softmax stats at i (t<128) || delta m=0 (t>=128) ----
  if (t < 128) {
    const int h = t >> 6, lane = t & 63;
    float m = -1e30f;
    for (int e = lane; e < nE2; e += 64) m = fmaxf(m, S.slog[h][e]);
    for (int o = 1; o < 64; o <<= 1) m = fmaxf(m, __shfl_xor(m, o));
    float ssum = 0.f;
    for (int e = lane; e < nE2; e += 64) {
      const float w = __expf(S.slog[h][e]-m); S.sw[h][e] = w; ssum += w;
    }
    for (int o = 1; o < 64; o <<= 1) ssum += __shfl_xor(ssum, o);
    if (lane == 0) S.sinv[h] = 1.f/(ssum + 1e-16f);
  } else {
    delta_one(S, 0, nMl, i, t);
  }
  __syncthreads();

  // ---- stage E: agg+elu at i (t<64) || delta m=1 (t>=128) ----
  if (t < 64) {
    float a0 = 0.f, a1 = 0.f;
    for (int e = 0; e < nE2; ++e) {
      const int s = S.ssrc2[e];
      const float* xs = (s == i) ? S.sxlVi : (g_xl0 + s*128);
      a0 += S.sw[0][e]*xs[t];
      a1 += S.sw[1][e]*xs[64+t];
    }
    float g = 0.5f*(a0*S.sinv[0] + a1*S.sinv[1]) + g_w[OFF_G1BIAS + t];
    g = g > 0.f ? g : expm1f(g);
    S.sgi[t] = g;
  } else if (t >= 128) {
    delta_one(S, 1, nMl, i, t);
  }
  __syncthreads();

  // ---- rare extra delta rounds (nM > 2) ----
  for (int m = 2; m < nMl; ++m) {
    if (t >= 128) delta_one(S, m, nMl, i, t);
    __syncthreads();
  }

  // ---- stage G: xr2i (t<128) || finalize g1m (t>=128) ----
  if (t < 128) {
    float v = g_w[OFF_G2BR + t];
    #pragma unroll
    for (int k = 0; k < 64; ++k) v += S.sgi[k]*g_w[OFF_G2WR + k*128+t];
    S.xr2i[t] = v;
  } else {
    for (int idx = t - 128; idx < nMl*64; idx += 128) {
      const int m = idx >> 6, c = idx & 63;
      float g = 0.5f*(S.rtmp[m*128+c] + S.rtmp[m*128+64+c]) + g_w[OFF_G1BIAS + c];
      g = g > 0.f ? g : expm1f(g);
      S.g1m[m*64+c] = g;
    }
  }
  __syncthreads();

  // ---- stage H: per-edge xl2 (changed sources recomputed) ----
  for (int idx = t; idx < nE2*128; idx += 256) {
    const int e = idx >> 7, c = idx & 127, s = S.ssrc2[e];
    const int sl = S.slotOf[s];
    float v;
    if (sl >= 0) {
      const float* g1r = (sl == 0) ? S.sgi : (S.g1m + (sl-1)*64);
      v = g_w[OFF_G2BL + c];
      #pragma unroll
      for (int k = 0; k < 64; ++k) v += g1r[k]*g_w[OFF_G2WL + k*128+c];
    } else {
      v = g_xl2_0[s*128+c];
    }
    S.xl2e[e*128+c] = v;
  }
  __syncthreads();

  // ---- stage I: layer-2 logits ----
  for (int idx = t; idx < nE2*2; idx += 256) {
    const int e = idx >> 1, h = idx & 1;
    const float* xle = S.xl2e + e*128 + h*64;
    float acc = 0.f;
    #pragma unroll
    for (int c = 0; c < 64; ++c) {
      float v = xle[c] + S.xr2i[h*64+c];
      v = v > 0.f ? v : 0.2f*v;
      acc += S.satt2[h*64+c]*v;
    }
    S.slog[h][e] = acc;
  }
  __syncthreads();

  // ---- stage J: layer-2 softmax stats ----
  if (t < 128) {
    const int h = t >> 6, lane = t & 63;
    float m = -1e30f;
    for (int e = lane; e < nE2; e += 64) m = fmaxf(m, S.slog[h][e]);
    for (int o = 1; o < 64; o <<= 1) m = fmaxf(m, __shfl_xor(m, o));
    float ssum = 0.f;
    for (int e = lane; e < nE2; e += 64) {
      const float w = __expf(S.slog[h][e]-m); S.sw[h][e] = w; ssum += w;
    }
    for (int o = 1; o < 64; o <<= 1) ssum += __shfl_xor(ssum, o);
    if (lane == 0) S.sinv[h] = 1.f/(ssum + 1e-16f);
  }
  __syncthreads();

  // ---- stage K: layer-2 agg + elu (both heads, t<64) ----
  if (t < 64) {
    float a0 = 0.f, a1 = 0.f;
    for (int e = 0; e < nE2; ++e) {
      a0 += S.sw[0][e]*S.xl2e[e*128 + t];
      a1 += S.sw[1][e]*S.xl2e[e*128 + 64 + t];
    }
    float g = 0.5f*(a0*S.sinv[0] + a1*S.sinv[1]) + g_w[OFF_G2BIAS + t];
    g = g > 0.f ? g : expm1f(g);
    S.sg[t] = g;
  }
  __syncthreads();

  // ---- stage L: reconstruction head + tanh + store ----
  if (t < 64) {
    float v = g_w[OFF_RECB + t];
    #pragma unroll
    for (int c = 0; c < 64; ++c) v += S.sg[c]*g_w[OFF_RECW + c*64+t];
    const float r = tanhf(v);
    if (g_f32) ((float*)out)[i*64+t] = r;
    else       ((__hip_bfloat16*)out)[i*64+t] = __float2bfloat16(r);
  }
}

// ---------------------------------------------------------------------------
extern "C" void kernel_launch(void* const* d_in, const int* in_sizes, int n_in,
                              void* d_out, int out_size, void* d_ws, size_t ws_size,
                              hipStream_t stream)
{
  const int* ei = (const int*)d_in[2];
  const int E = in_sizes[2] / 2;

  k_init<<<45, 256, 0, stream>>>(
      d_in[0], d_in[1], d_in[3], d_in[4], d_in[5], d_in[6], d_in[7],
      d_in[8], d_in[9], d_in[10], d_in[11], d_in[12], d_in[13], d_in[14],
      d_in[15], d_in[16], d_in[17], d_in[18], d_in[19], d_in[20], d_in[21],
      d_in[22], d_in[23], d_in[24], d_in[25],
      in_sizes[0], ei, E);
  k_dense<<<NN, 128, 0, stream>>>();
  k_l1base<<<NN, 128, 0, stream>>>();
  k_periter<<<NN, 256, 0, stream>>>(d_out);
}